// Round 1
// baseline (798.475 us; speedup 1.0000x reference)
//
#include <hip/hip_runtime.h>
#include <math.h>

#define NEGV -1e30f

__device__ __forceinline__ float wave_reduce_max(float v) {
#pragma unroll
  for (int off = 32; off >= 1; off >>= 1) v = fmaxf(v, __shfl_xor(v, off, 64));
  return v;
}
__device__ __forceinline__ float wave_reduce_sum(float v) {
#pragma unroll
  for (int off = 32; off >= 1; off >>= 1) v += __shfl_xor(v, off, 64);
  return v;
}

// Kernel A: lse[b*T+t] = logsumexp_c(log_probs[b,t,:]) if t < input_len[b] else 0
// one wave per row; C == 1024 assumed (4 x float4 per lane).
__global__ __launch_bounds__(256) void lse_kernel(
    const float* __restrict__ lp, const int* __restrict__ ilen,
    float* __restrict__ lse, int B, int T, int C) {
  const int wave = threadIdx.x >> 6;
  const int lane = threadIdx.x & 63;
  const int row = blockIdx.x * 4 + wave;
  if (row >= B * T) return;
  const int b = row / T;
  const int t = row - b * T;
  const float4* p = (const float4*)(lp + (size_t)row * C);
  float4 v0 = p[lane];
  float4 v1 = p[lane + 64];
  float4 v2 = p[lane + 128];
  float4 v3 = p[lane + 192];
  float m = fmaxf(fmaxf(fmaxf(v0.x, v0.y), fmaxf(v0.z, v0.w)),
                  fmaxf(fmaxf(fmaxf(v1.x, v1.y), fmaxf(v1.z, v1.w)),
                        fmaxf(fmaxf(fmaxf(v2.x, v2.y), fmaxf(v2.z, v2.w)),
                              fmaxf(fmaxf(v3.x, v3.y), fmaxf(v3.z, v3.w)))));
  m = wave_reduce_max(m);
  float s = __expf(v0.x - m) + __expf(v0.y - m) + __expf(v0.z - m) + __expf(v0.w - m) +
            __expf(v1.x - m) + __expf(v1.y - m) + __expf(v1.z - m) + __expf(v1.w - m) +
            __expf(v2.x - m) + __expf(v2.y - m) + __expf(v2.z - m) + __expf(v2.w - m) +
            __expf(v3.x - m) + __expf(v3.y - m) + __expf(v3.z - m) + __expf(v3.w - m);
  s = wave_reduce_sum(s);
  if (lane == 0) lse[row] = (t < ilen[b]) ? (m + __logf(s)) : 0.0f;
}

// Kernel B: norm[b] = sum_t lse[b*T+t]
__global__ __launch_bounds__(256) void norm_kernel(const float* __restrict__ lse,
                                                   float* __restrict__ norm, int T) {
  const int b = blockIdx.x;
  const int lane = threadIdx.x & 63;
  const int wave = threadIdx.x >> 6;
  float s = 0.0f;
  for (int i = threadIdx.x; i < T; i += 256) s += lse[(size_t)b * T + i];
  s = wave_reduce_sum(s);
  __shared__ float red[4];
  if (lane == 0) red[wave] = s;
  __syncthreads();
  if (threadIdx.x == 0) norm[b] = red[0] + red[1] + red[2] + red[3];
}

// Kernel C: sequential CTC forward DP. One wave (64 lanes) per batch element.
// Lane l owns states s = 4l+j, j in [0,4) ; lane 63 additionally owns s=256 (j=4).
// All lanes compute j=4 unconditionally (redundant copy of state 4l+4) -- harmless.
__global__ __launch_bounds__(64) void ctc_dp_kernel(
    const float* __restrict__ lp, const int* __restrict__ targets,
    const int* __restrict__ ilen, const int* __restrict__ tlen,
    const float* __restrict__ norm, float* __restrict__ out,
    int T, int C, int L) {
  const int b = blockIdx.x;
  const int l = threadIdx.x;
  const int len = ilen[b];
  const int tl = tlen[b];
  const int Sb = 2 * tl + 1;
  const int* tg = targets + (size_t)b * L;
  const float* row0 = lp + (size_t)b * T * C;

  int e[5];
  bool sk[5];
  bool valid[5];
#pragma unroll
  for (int j = 0; j < 5; ++j) {
    int s = 4 * l + j;            // <= 256 < S
    bool odd = (s & 1) != 0;
    int li = (s - 1) >> 1;        // label index for odd s (<= 127)
    int lab = odd ? tg[li] : 0;
    e[j] = lab;
    sk[j] = (odd && s >= 3) ? (tg[li] != tg[li - 1]) : false;
    valid[j] = s < Sb;
  }

  // t = 0 init: only states 0,1 alive
  float a[5];
#pragma unroll
  for (int j = 0; j < 5; ++j) {
    int s = 4 * l + j;
    float v = row0[e[j]];
    a[j] = (s < 2) ? v : NEGV;    // s<2 implies valid (Sb >= 129)
  }

  auto loadg = [&](float g[5], int t) {
    const float* row = row0 + (size_t)t * C;
#pragma unroll
    for (int j = 0; j < 5; ++j) g[j] = row[e[j]];
  };

  auto step = [&](const float g[5]) {
    float up1 = __shfl_up(a[3], 1, 64);  // alpha[4l-1]
    float up2 = __shfl_up(a[2], 1, 64);  // alpha[4l-2]
    if (l == 0) { up1 = NEGV; up2 = NEGV; }
    float p1s0 = up1, p1s1 = a[0], p1s2 = a[1], p1s3 = a[2], p1s4 = a[3];
    float p2s0 = up2, p2s1 = up1, p2s2 = a[0], p2s3 = a[1], p2s4 = a[2];
    float n[5];
    {
      float p1[5] = {p1s0, p1s1, p1s2, p1s3, p1s4};
      float p2[5] = {p2s0, p2s1, p2s2, p2s3, p2s4};
#pragma unroll
      for (int j = 0; j < 5; ++j) {
        float q0 = a[j];
        float q1 = p1[j];
        float q2 = sk[j] ? p2[j] : NEGV;
        float m = fmaxf(q0, fmaxf(q1, q2));
        float ss = __expf(q0 - m) + __expf(q1 - m) + __expf(q2 - m);
        n[j] = g[j] + m + __logf(ss);
      }
    }
#pragma unroll
    for (int j = 0; j < 5; ++j) a[j] = valid[j] ? n[j] : NEGV;
  };

  // software-pipelined main loop, depth-2 prefetch
  float g1[5], g2[5];
  loadg(g1, 1);
  loadg(g2, 2 < T ? 2 : T - 1);
  int t = 1;
  for (; t + 1 < len; t += 2) {
    float gn1[5], gn2[5];
    int t2 = t + 2 < T ? t + 2 : T - 1;
    int t3 = t + 3 < T ? t + 3 : T - 1;
    loadg(gn1, t2);
    step(g1);
    loadg(gn2, t3);
    step(g2);
#pragma unroll
    for (int j = 0; j < 5; ++j) { g1[j] = gn1[j]; g2[j] = gn2[j]; }
  }
  if (t < len) step(g1);

  // epilogue: collect alpha[Sb-1], alpha[Sb-2]
  __shared__ float af[257];
#pragma unroll
  for (int j = 0; j < 4; ++j) af[4 * l + j] = a[j];
  if (l == 63) af[256] = a[4];
  __syncthreads();
  if (l == 0) {
    float a1 = af[Sb - 1];
    float a2 = af[Sb - 2];
    float m = fmaxf(a1, a2);
    float llh = m + __logf(__expf(a1 - m) + __expf(a2 - m));
    out[b] = -(llh - norm[b]);
  }
}

extern "C" void kernel_launch(void* const* d_in, const int* in_sizes, int n_in,
                              void* d_out, int out_size, void* d_ws, size_t ws_size,
                              hipStream_t stream) {
  const float* lp = (const float*)d_in[0];
  const int* targets = (const int*)d_in[1];
  const int* ilen = (const int*)d_in[2];
  const int* tlen = (const int*)d_in[3];
  float* out = (float*)d_out;

  const int B = in_sizes[2];              // 32
  const int L = in_sizes[1] / B;          // 128
  const int C = 1024;                     // per reference
  const int T = in_sizes[0] / (B * C);    // 1600

  float* lse = (float*)d_ws;              // B*T floats
  float* norm = lse + (size_t)B * T;      // B floats

  const int rows = B * T;
  lse_kernel<<<(rows + 3) / 4, 256, 0, stream>>>(lp, ilen, lse, B, T, C);
  norm_kernel<<<B, 256, 0, stream>>>(lse, norm, T);
  ctc_dp_kernel<<<B, 64, 0, stream>>>(lp, targets, ilen, tlen, norm, out, T, C, L);
}